// Round 4
// baseline (141.425 us; speedup 1.0000x reference)
//
#include <hip/hip_runtime.h>

#define TT    2048
#define SS    512
#define NB    16
#define EPEN  0.60653065971263342f   // exp(-0.5)
#define NCHUNK 64
#define CLEN   32

typedef __attribute__((ext_vector_type(4))) float  floatx4;
typedef __attribute__((ext_vector_type(8))) short  bf16x8;

__device__ __forceinline__ ushort f2bf(float x) {   // RNE fp32 -> bf16
  unsigned u = __float_as_uint(x);
  u += 0x7fffu + ((u >> 16) & 1u);
  return (ushort)(u >> 16);
}

// ---------------- kernel 0: W -> transposed bf16  Wt[col][k] ---------------
__global__ __launch_bounds__(256) void prep_kernel(
    const float* __restrict__ Wa, const float* __restrict__ Ws,
    const float* __restrict__ Wst, ushort* __restrict__ Wt)
{
  int idx = blockIdx.x * 256 + threadIdx.x;       // 336*512 = 172032
  if (idx >= 336 * 512) return;
  int col = idx >> 9, k = idx & 511;
  float v;
  if (col < 288)      v = Wa [(size_t)k * 288 + col];
  else if (col < 320) v = Ws [(size_t)k * 32  + (col - 288)];
  else                v = Wst[(size_t)k * 16  + (col - 320)];
  Wt[idx] = f2bf(v);
}

// ---------------- kernel A: MFMA GEMM (no LDS staging) + softmax -> coef ---
// block: 32 rows x 336 cols, 4 waves. A & B fragments loaded straight from
// global in MFMA layout; no barriers in the K-loop.
__global__ __launch_bounds__(256) void proj_kernel(
    const float* __restrict__ s_i,
    const ushort* __restrict__ Wt,
    const int*   __restrict__ actions,
    float4*      __restrict__ coef)
{
  __shared__ float lg[32][344];

  const int tid  = threadIdx.x;
  const int wave = tid >> 6, lane = tid & 63;
  const int q = lane >> 4, rc = lane & 15;
  const int row0 = blockIdx.x * 32;

  const int mbase  = (wave >> 1) * 16;
  const int ntile0 = (wave & 1) * 11;
  const int ntiles = (wave & 1) ? 10 : 11;

  int arow = row0 + mbase + rc; if (arow > TT) arow = TT;
  const float*  aptr  = s_i + (size_t)arow * SS + q * 8;
  const ushort* bbase = Wt + (size_t)(ntile0 * 16 + rc) * 512 + q * 8;

  floatx4 acc[11];
  #pragma unroll
  for (int n = 0; n < 11; ++n) acc[n] = (floatx4)(0.f);

  #pragma unroll 2
  for (int kt = 0; kt < 16; ++kt) {
    float4 a0 = *(const float4*)(aptr + kt * 32);
    float4 a1 = *(const float4*)(aptr + kt * 32 + 4);
    bf16x8 af;
    af[0] = (short)f2bf(a0.x); af[1] = (short)f2bf(a0.y);
    af[2] = (short)f2bf(a0.z); af[3] = (short)f2bf(a0.w);
    af[4] = (short)f2bf(a1.x); af[5] = (short)f2bf(a1.y);
    af[6] = (short)f2bf(a1.z); af[7] = (short)f2bf(a1.w);
    #pragma unroll
    for (int n = 0; n < 11; ++n) {
      if (n < ntiles) {
        bf16x8 bf = *(const bf16x8*)(bbase + (size_t)n * 16 * 512 + kt * 32);
        acc[n] = __builtin_amdgcn_mfma_f32_16x16x32_bf16(af, bf, acc[n], 0, 0, 0);
      }
    }
  }

  // ---- write logits to LDS (C/D layout: row = q*4+reg, col = rc)
  #pragma unroll
  for (int n = 0; n < 11; ++n) {
    if (n < ntiles) {
      int colt = ntile0 + n;
      #pragma unroll
      for (int reg = 0; reg < 4; ++reg)
        lg[mbase + q * 4 + reg][colt * 16 + rc] = acc[n][reg];
    }
  }
  __syncthreads();

  // ---- softmax epilogue: 32 rows x 16 b
  #pragma unroll
  for (int h = 0; h < 2; ++h) {
    const int r = h * 16 + (tid >> 4), b = tid & 15;
    const int row = row0 + r;
    if (row < TT) {
      float m = -3.4e38f;
      #pragma unroll
      for (int a = 0; a < 18; ++a) m = fmaxf(m, lg[r][b * 18 + a]);
      float sum = 0.f;
      #pragma unroll
      for (int a = 0; a < 18; ++a) sum += __expf(lg[r][b * 18 + a] - m);
      int act = actions[row];
      float aprob = __expf(lg[r][b * 18 + act] - m) / sum;

      float x0 = lg[r][288 + 2 * b], x1 = lg[r][288 + 2 * b + 1];
      float mm = fmaxf(x0, x1);
      float e0 = __expf(x0 - mm), e1 = __expf(x1 - mm);
      float inv = 1.f / (e0 + e1);

      float ms = -3.4e38f;
      #pragma unroll
      for (int j = 0; j < 16; ++j) ms = fmaxf(ms, lg[r][320 + j]);
      float ssum = 0.f;
      #pragma unroll
      for (int j = 0; j < 16; ++j) ssum += __expf(lg[r][320 + j] - ms);
      float stp = __expf(lg[r][320 + b] - ms) / ssum;

      coef[(size_t)row * NB + b] = make_float4(e0 * inv, e1 * inv, stp, aprob);
    } else if (row == TT) {
      float x0 = lg[r][288 + 2 * b], x1 = lg[r][288 + 2 * b + 1];
      float mm = fmaxf(x0, x1);
      float e0 = __expf(x0 - mm), e1 = __expf(x1 - mm);
      coef[(size_t)TT * NB + b] = make_float4(1.f, 0.f, 0.f, e0 / (e0 + e1));
    }
  }
}

// ---------------- kernel B: pass1 — chunk transfer matrices + w-vectors ----
// Mws now COLUMN-major per chunk: Mws[k*256 + c*16 + r] = M_k[r][c]
__global__ __launch_bounds__(64) void pass1_kernel(
    const float4* __restrict__ coef,
    float* __restrict__ Wws, float* __restrict__ Mws)
{
  const int chunk = blockIdx.x * 4 + (threadIdx.x >> 4);
  const int c = threadIdx.x & 15;
  const int i0 = chunk * CLEN + 1;

  float G[16];
  #pragma unroll
  for (int r = 0; r < 16; ++r) G[r] = (r == c) ? 1.f : 0.f;

  float4 cfA[16], cfB[16];
  #pragma unroll
  for (int r = 0; r < 16; ++r) cfA[r] = coef[(size_t)i0 * 16 + r];
  #pragma unroll
  for (int r = 0; r < 16; ++r) cfB[r] = coef[(size_t)(i0 + 1) * 16 + r];

#define P1BODY(CUR, NXT, J)                                                  \
  {                                                                          \
    if ((J) + 2 < CLEN) {                                                    \
      _Pragma("unroll")                                                      \
      for (int r = 0; r < 16; ++r)                                           \
        NXT[r] = coef[(size_t)(i0 + (J) + 2) * 16 + r];                      \
    }                                                                        \
    float ta = 0.f, tb = 0.f, tc = 0.f, td = 0.f;                            \
    _Pragma("unroll")                                                        \
    for (int r = 0; r < 4; ++r) {                                            \
      ta = fmaf(CUR[r].y,      G[r],      ta);                               \
      tb = fmaf(CUR[r + 4].y,  G[r + 4],  tb);                               \
      tc = fmaf(CUR[r + 8].y,  G[r + 8],  tc);                               \
      td = fmaf(CUR[r + 12].y, G[r + 12], td);                               \
    }                                                                        \
    float et = EPEN * ((ta + tb) + (tc + td));                               \
    _Pragma("unroll")                                                        \
    for (int r = 0; r < 16; ++r)                                             \
      G[r] = fmaf(CUR[r].x, G[r], CUR[r].z * et);                            \
    float wa = 0.f, wb = 0.f, wc = 0.f, wd = 0.f;                            \
    _Pragma("unroll")                                                        \
    for (int r = 0; r < 4; ++r) {                                            \
      wa = fmaf(CUR[r].w,      G[r],      wa);                               \
      wb = fmaf(CUR[r + 4].w,  G[r + 4],  wb);                               \
      wc = fmaf(CUR[r + 8].w,  G[r + 8],  wc);                               \
      wd = fmaf(CUR[r + 12].w, G[r + 12], wd);                               \
    }                                                                        \
    Wws[(size_t)(chunk * CLEN + (J)) * 16 + c] = (wa + wb) + (wc + wd);      \
  }

  for (int j = 0; j < CLEN; j += 2) {
    P1BODY(cfA, cfB, j);
    P1BODY(cfB, cfA, j + 1);
  }
#undef P1BODY

  #pragma unroll
  for (int rr = 0; rr < 4; ++rr) {
    float4 v = make_float4(G[rr * 4], G[rr * 4 + 1], G[rr * 4 + 2], G[rr * 4 + 3]);
    *(float4*)(Mws + chunk * 256 + c * 16 + rr * 4) = v;
  }
}

// ---------------- kernel C: scan2 — 1-wave walk, then parallel terms -------
template <int N>
__device__ __forceinline__ float ror_add(float v) {
  int r = __builtin_amdgcn_mov_dpp(__float_as_int(v), 0x120 + N, 0xF, 0xF, true);
  return v + __int_as_float(r);
}
__device__ __forceinline__ float reduce16(float v) {
  v = ror_add<8>(v); v = ror_add<4>(v); v = ror_add<2>(v); v = ror_add<1>(v);
  return v;
}

__global__ __launch_bounds__(512) void scan2_kernel(
    const float4* __restrict__ coef,
    const float* __restrict__ Wws, const float* __restrict__ Mws,
    float* __restrict__ out)
{
  __shared__ float pk[NCHUNK][16];   // chunk-start p vectors (scaled)
  __shared__ int   Ee[NCHUNK];       // cumulative pow-2 exponents at chunk start
  __shared__ float racc[33];         // 32 group partials + term0
  __shared__ int   kacc[32];

  const int tid = threadIdx.x;

  if (tid < 64) {                    // ---- wave 0: sequential chunk walk ----
    const int g = tid >> 4, c = tid & 15;
    float4 c0 = coef[c];
    float p = c0.z;
    float U0 = reduce16(c0.w * p);
    if (tid == 0) { racc[32] = __logf(U0); Ee[0] = 0; }
    if (g == 0) pk[0][c] = p;
    int Ecum = 0;

    float4 mcur  = *(const float4*)(Mws + 0 * 256 + c * 16 + g * 4);
    float4 mnext = *(const float4*)(Mws + 1 * 256 + c * 16 + g * 4);
    for (int k = 0; k < NCHUNK; ++k) {
      float4 mc = mcur; mcur = mnext;
      if (k + 2 < NCHUNK)
        mnext = *(const float4*)(Mws + (size_t)(k + 2) * 256 + c * 16 + g * 4);
      // y[4g+j] = sum_c M[4g+j][c] * p[c]
      float y0 = reduce16(mc.x * p);
      float y1 = reduce16(mc.y * p);
      float y2 = reduce16(mc.z * p);
      float y3 = reduce16(mc.w * p);
      int sel = c & 3;
      float z = (sel == 0) ? y0 : (sel == 1) ? y1 : (sel == 2) ? y2 : y3;
      int src = (((c >> 2) * 16 + c) << 2);
      float pn = __int_as_float(
          __builtin_amdgcn_ds_bpermute(src, __float_as_int(z)));
      int bits = __builtin_amdgcn_readfirstlane(__float_as_int(pn));
      int eb = (bits >> 23) & 255;
      Ecum += eb - 127;
      p = pn * __int_as_float((254 - eb) << 23);   // * 2^{-(eb-127)}, exact
      if (k + 1 < NCHUNK) {
        if (g == 0) pk[k + 1][c] = p;
        if (tid == 0) Ee[k + 1] = Ecum;
      }
    }
  }
  __syncthreads();

  // ---- all 8 waves: 32 groups x 64 steps of parallel term dot-products ----
  const int gg = tid >> 4, c = tid & 15;
  float acc = 0.f;
  int klocal = 0;
  #pragma unroll
  for (int h = 0; h < 2; ++h) {
    const int k = gg * 2 + h;
    const float pc = pk[k][c];
    klocal += CLEN * Ee[k];
    #pragma unroll
    for (int j = 0; j < CLEN; ++j) {
      float w = Wws[(size_t)(k * CLEN + j) * 16 + c];
      float U = reduce16(w * pc);
      acc += __logf(U);
    }
  }
  if (c == 0) { racc[gg] = acc; kacc[gg] = klocal; }
  __syncthreads();
  if (tid == 0) {
    double s = (double)racc[32];
    long long K = 0;
    for (int i = 0; i < 32; ++i) { s += (double)racc[i]; K += (long long)kacc[i]; }
    out[0] = (float)(s + 0.6931471805599453 * (double)K);
  }
}

extern "C" void kernel_launch(void* const* d_in, const int* in_sizes, int n_in,
                              void* d_out, int out_size, void* d_ws, size_t ws_size,
                              hipStream_t stream) {
  const float* s_i = (const float*)d_in[0];
  const float* Wa  = (const float*)d_in[1];
  const float* Ws  = (const float*)d_in[2];
  const float* Wst = (const float*)d_in[3];
  const int*   act = (const int*)d_in[4];

  char* ws = (char*)d_ws;
  float4* coef = (float4*)ws;                        //   524,544 B
  float*  Wws  = (float*)(ws + 524544);              // + 131,072 B
  float*  Mws  = (float*)(ws + 524544 + 131072);     // +  65,536 B
  ushort* Wt   = (ushort*)(ws + 524544 + 131072 + 65536);  // + 344,064 B

  prep_kernel <<<672, 256, 0, stream>>>(Wa, Ws, Wst, Wt);
  proj_kernel <<<65,  256, 0, stream>>>(s_i, Wt, act, coef);
  pass1_kernel<<<16,  64,  0, stream>>>(coef, Wws, Mws);
  scan2_kernel<<<1,   512, 0, stream>>>(coef, Wws, Mws, (float*)d_out);
}